// Round 3
// baseline (2199.458 us; speedup 1.0000x reference)
//
#include <hip/hip_runtime.h>

#define NB 1024   // batch
#define TT 32     // encoder length
#define DIN 256   // input dim
#define HD 256    // hidden dim
#define NC 38     // classes
#define NSTEP 26  // decode steps

typedef unsigned short ushort_t;
typedef __attribute__((ext_vector_type(8))) short bf16x8;
typedef __attribute__((ext_vector_type(8))) unsigned short us8;
typedef __attribute__((ext_vector_type(4))) float f32x4;

#define GLOAD_LDS16(g, l) \
  __builtin_amdgcn_global_load_lds((const __attribute__((address_space(1))) unsigned int*)(g), \
                                   (__attribute__((address_space(3))) unsigned int*)(l), 16, 0, 0)

__device__ __forceinline__ float sigmoidf_(float x) {
    return 1.0f / (1.0f + expf(-x));
}
__device__ __forceinline__ unsigned short f2bf(float x) {
    union { float f; unsigned u; } v; v.f = x;
    unsigned r = v.u + 0x7fff + ((v.u >> 16) & 1);   // RNE
    return (unsigned short)(r >> 16);
}
__device__ __forceinline__ float bf2f(unsigned short h) {
    union { unsigned u; float f; } v; v.u = ((unsigned)h) << 16;
    return v.f;
}

// ---------------------------------------------------------------------------
// Weight prep: split-bf16.  B pattern per row: [hi | lo | hi] over virtual K.
// ---------------------------------------------------------------------------
__global__ void prep_B2g(const float* __restrict__ w_ih, const float* __restrict__ w_hh,
                         ushort_t* __restrict__ B2)
{
    int j = blockIdx.x;  // 1024 rows
    for (int k = threadIdx.x; k < 512; k += 256) {
        float x = (k < 256) ? w_ih[(size_t)j * 294 + k] : w_hh[(size_t)j * 256 + (k - 256)];
        unsigned short hi = f2bf(x);
        unsigned short lo = f2bf(x - bf2f(hi));
        size_t r = (size_t)j * 1536;
        B2[r + k] = hi; B2[r + 512 + k] = lo; B2[r + 1024 + k] = hi;
    }
}

__global__ void prep_B2i(const float* __restrict__ w_i2h, ushort_t* __restrict__ B2i)
{
    int n = blockIdx.x;  // 256 rows
    int k = threadIdx.x;
    float x = w_i2h[(size_t)n * 256 + k];
    unsigned short hi = f2bf(x);
    unsigned short lo = f2bf(x - bf2f(hi));
    size_t r = (size_t)n * 768;
    B2i[r + k] = hi; B2i[r + 256 + k] = lo; B2i[r + 512 + k] = hi;
}

// ---------------------------------------------------------------------------
// hproj MFMA: Hproj[m][n] = sum_k enc[m][k] * w_i2h[n][k]
// M=32768, N=256, virtual K=768 (A parts [hi|hi|lo] from fp32 enc on the fly).
// BM=128, BN=128, BK=64. grid (256,2), 256 thr, 2x2 waves, wave tile 64x64.
// ---------------------------------------------------------------------------
__global__ __launch_bounds__(256) void hproj_mfma(
    const float* __restrict__ enc, const ushort_t* __restrict__ B2i,
    float* __restrict__ Hproj)
{
    __shared__ ushort_t lA[128 * 64];  // [m][g_phys] 16B chunks, 16 KB
    __shared__ ushort_t lB[128 * 64];  // [n][g_phys], 16 KB

    const int tid = threadIdx.x;
    const int lane = tid & 63, wid = tid >> 6;
    const int wm = wid >> 1, wn = wid & 1;
    const int m0 = blockIdx.x * 128, n0 = blockIdx.y * 128;

    f32x4 acc[4][4];
    const f32x4 fz = {0.f, 0.f, 0.f, 0.f};
#pragma unroll
    for (int i = 0; i < 4; i++)
#pragma unroll
        for (int j = 0; j < 4; j++) acc[i][j] = fz;

    for (int kc = 0; kc < 12; kc++) {
        // B stage: async global->LDS, pre-swizzled source
#pragma unroll
        for (int i = 0; i < 4; i++) {
            int c = tid + i * 256;
            int n = c >> 3, gp = c & 7;
            int gl = gp ^ (n & 7);
            const ushort_t* src = &B2i[(size_t)(n0 + n) * 768 + kc * 64 + gl * 8];
            GLOAD_LDS16(src, &lB[c * 8]);
        }
        // A stage: load fp32 enc, convert hi/lo, swizzled ds_write
#pragma unroll
        for (int i = 0; i < 4; i++) {
            int c = tid + i * 256;
            int m = c >> 3, gp = c & 7;
            int gl = gp ^ (m & 7);
            int vk = kc * 64 + gl * 8;
            int part = vk >> 8;        // 0,1 -> hi ; 2 -> lo
            int ko = vk & 255;
            const float* src = &enc[(size_t)(m0 + m) * 256 + ko];
            float4 x0 = *(const float4*)src;
            float4 x1 = *(const float4*)(src + 4);
            float xs[8] = {x0.x, x0.y, x0.z, x0.w, x1.x, x1.y, x1.z, x1.w};
            us8 v;
            if (part < 2) {
#pragma unroll
                for (int j = 0; j < 8; j++) v[j] = f2bf(xs[j]);
            } else {
#pragma unroll
                for (int j = 0; j < 8; j++) {
                    unsigned short hh = f2bf(xs[j]);
                    v[j] = f2bf(xs[j] - bf2f(hh));
                }
            }
            *(us8*)&lA[c * 8] = v;
        }
        asm volatile("s_waitcnt vmcnt(0)" ::: "memory");
        __syncthreads();

#pragma unroll
        for (int kk = 0; kk < 2; kk++) {
            bf16x8 af[4], bfr[4];
            int g = kk * 4 + (lane >> 4);
#pragma unroll
            for (int mi = 0; mi < 4; mi++) {
                int m = wm * 64 + mi * 16 + (lane & 15);
                af[mi] = *(const bf16x8*)&lA[m * 64 + ((g ^ (m & 7)) << 3)];
            }
#pragma unroll
            for (int ni = 0; ni < 4; ni++) {
                int n = wn * 64 + ni * 16 + (lane & 15);
                bfr[ni] = *(const bf16x8*)&lB[n * 64 + ((g ^ (n & 7)) << 3)];
            }
#pragma unroll
            for (int mi = 0; mi < 4; mi++)
#pragma unroll
                for (int ni = 0; ni < 4; ni++)
                    acc[mi][ni] = __builtin_amdgcn_mfma_f32_16x16x32_bf16(af[mi], bfr[ni], acc[mi][ni], 0, 0, 0);
        }
        __syncthreads();
    }

#pragma unroll
    for (int mi = 0; mi < 4; mi++)
#pragma unroll
        for (int r = 0; r < 4; r++) {
            int row = m0 + wm * 64 + mi * 16 + (lane >> 4) * 4 + r;
#pragma unroll
            for (int ni = 0; ni < 4; ni++) {
                int col = n0 + wn * 64 + ni * 16 + (lane & 15);
                Hproj[(size_t)row * 256 + col] = acc[mi][ni][r];
            }
        }
}

// ---------------------------------------------------------------------------
// gates MFMA: gates[b][j] = sum_k x[b][k]*W[j][k] (+biases +onehot col)
// x = [ctx|h] fp32 (converted on the fly), W from precomputed B2g.
// M=1024, N=1024, virtual K=1536. BM=128, BN=64, BK=64. grid (8,16).
// ---------------------------------------------------------------------------
__global__ __launch_bounds__(256) void gates_mfma(
    const float* __restrict__ ctx, const float* __restrict__ h,
    const ushort_t* __restrict__ B2, const float* __restrict__ b_ih,
    const float* __restrict__ b_hh, const float* __restrict__ w_ih,
    const int* __restrict__ text, int step, float* __restrict__ gates)
{
    __shared__ ushort_t lA[128 * 64];  // 16 KB
    __shared__ ushort_t lB[64 * 64];   // 8 KB

    const int tid = threadIdx.x;
    const int lane = tid & 63, wid = tid >> 6;
    const int wm = wid >> 1, wn = wid & 1;
    const int m0 = blockIdx.x * 128, n0 = blockIdx.y * 64;

    f32x4 acc[4][2];
    const f32x4 fz = {0.f, 0.f, 0.f, 0.f};
#pragma unroll
    for (int i = 0; i < 4; i++) { acc[i][0] = fz; acc[i][1] = fz; }

    for (int kc = 0; kc < 24; kc++) {
        // B stage (bf16 precomputed): async, pre-swizzled source
#pragma unroll
        for (int i = 0; i < 2; i++) {
            int c = tid + i * 256;
            int n = c >> 3, gp = c & 7;
            int gl = gp ^ (n & 7);
            const ushort_t* src = &B2[(size_t)(n0 + n) * 1536 + kc * 64 + gl * 8];
            GLOAD_LDS16(src, &lB[c * 8]);
        }
        // A stage: fp32 ctx/h -> hi/lo bf16, swizzled ds_write
#pragma unroll
        for (int i = 0; i < 4; i++) {
            int c = tid + i * 256;
            int m = c >> 3, gp = c & 7;
            int gl = gp ^ (m & 7);
            int vk = kc * 64 + gl * 8;
            int part = vk >> 9;        // /512 : 0,1 -> hi ; 2 -> lo
            int ko = vk & 511;
            const float* src = (ko < 256) ? &ctx[(size_t)(m0 + m) * 256 + ko]
                                          : &h[(size_t)(m0 + m) * 256 + (ko - 256)];
            float4 x0 = *(const float4*)src;
            float4 x1 = *(const float4*)(src + 4);
            float xs[8] = {x0.x, x0.y, x0.z, x0.w, x1.x, x1.y, x1.z, x1.w};
            us8 v;
            if (part < 2) {
#pragma unroll
                for (int j = 0; j < 8; j++) v[j] = f2bf(xs[j]);
            } else {
#pragma unroll
                for (int j = 0; j < 8; j++) {
                    unsigned short hh = f2bf(xs[j]);
                    v[j] = f2bf(xs[j] - bf2f(hh));
                }
            }
            *(us8*)&lA[c * 8] = v;
        }
        asm volatile("s_waitcnt vmcnt(0)" ::: "memory");
        __syncthreads();

#pragma unroll
        for (int kk = 0; kk < 2; kk++) {
            bf16x8 af[4], bfr[2];
            int g = kk * 4 + (lane >> 4);
#pragma unroll
            for (int mi = 0; mi < 4; mi++) {
                int m = wm * 64 + mi * 16 + (lane & 15);
                af[mi] = *(const bf16x8*)&lA[m * 64 + ((g ^ (m & 7)) << 3)];
            }
#pragma unroll
            for (int ni = 0; ni < 2; ni++) {
                int n = wn * 32 + ni * 16 + (lane & 15);
                bfr[ni] = *(const bf16x8*)&lB[n * 64 + ((g ^ (n & 7)) << 3)];
            }
#pragma unroll
            for (int mi = 0; mi < 4; mi++)
#pragma unroll
                for (int ni = 0; ni < 2; ni++)
                    acc[mi][ni] = __builtin_amdgcn_mfma_f32_16x16x32_bf16(af[mi], bfr[ni], acc[mi][ni], 0, 0, 0);
        }
        __syncthreads();
    }

#pragma unroll
    for (int mi = 0; mi < 4; mi++)
#pragma unroll
        for (int r = 0; r < 4; r++) {
            int row = m0 + wm * 64 + mi * 16 + (lane >> 4) * 4 + r;
            int cl = text[row * NSTEP + step];
#pragma unroll
            for (int ni = 0; ni < 2; ni++) {
                int col = n0 + wn * 32 + ni * 16 + (lane & 15);
                float v = acc[mi][ni][r] + b_ih[col] + b_hh[col]
                        + w_ih[(size_t)col * 294 + 256 + cl];
                gates[(size_t)row * 1024 + col] = v;
            }
        }
}

// ---------------------------------------------------------------------------
// recur: LSTM(step-1) + probs(step-1) + hp(step).  4 rows/block, 256 blocks.
// ---------------------------------------------------------------------------
#define RPB 4
__global__ __launch_bounds__(256) void recur_kernel(
    const float* __restrict__ gates,
    const float* __restrict__ w_h2h, const float* __restrict__ b_h2h,
    const float* __restrict__ w_gen, const float* __restrict__ b_gen,
    float* __restrict__ h, float* __restrict__ c,
    float* __restrict__ hp, float* __restrict__ probs, int step)
{
    __shared__ float hsh[RPB][HD];
    const int tid = threadIdx.x;
    const int b0 = blockIdx.x * RPB;

    if (step > 0) {
#pragma unroll
        for (int it = 0; it < RPB; it++) {
            int idx = tid + it * 256;
            int bl = idx >> 8, hh = idx & 255;
            int b = b0 + bl;
            float gi = gates[(size_t)b * 1024 + hh];
            float gf = gates[(size_t)b * 1024 + 256 + hh];
            float gg = gates[(size_t)b * 1024 + 512 + hh];
            float go = gates[(size_t)b * 1024 + 768 + hh];
            float cv = c[(size_t)b * HD + hh];
            float cn = sigmoidf_(gf) * cv + sigmoidf_(gi) * tanhf(gg);
            float hn = sigmoidf_(go) * tanhf(cn);
            c[(size_t)b * HD + hh] = cn;
            h[(size_t)b * HD + hh] = hn;
            hsh[bl][hh] = hn;
        }
        __syncthreads();
        // probs(step-1): 64 threads per row
        {
            int bl = tid >> 6, j = tid & 63;
            for (int jj = j; jj < NC; jj += 64) {
                float s = b_gen[jj];
                const float* wg = &w_gen[(size_t)jj * HD];
                for (int d = 0; d < HD; d += 4) {
                    float4 wv = *(const float4*)&wg[d];
                    float4 hv = *(const float4*)&hsh[bl][d];
                    s += wv.x * hv.x + wv.y * hv.y + wv.z * hv.z + wv.w * hv.w;
                }
                probs[((size_t)(b0 + bl) * NSTEP + (step - 1)) * NC + jj] = s;
            }
        }
    } else {
#pragma unroll
        for (int it = 0; it < RPB; it++) {
            int idx = tid + it * 256;
            int bl = idx >> 8, hh = idx & 255;
            hsh[bl][hh] = h[(size_t)(b0 + bl) * HD + hh];
        }
    }
    __syncthreads();
    if (step >= NSTEP) return;

    // hp[b][j] = dot(w_h2h[j], h[b]) + b_h2h[j], j = tid
    {
        float acc[RPB] = {0.f, 0.f, 0.f, 0.f};
        const float* wr = &w_h2h[(size_t)tid * HD];
        for (int d = 0; d < HD; d += 4) {
            float4 wv = *(const float4*)&wr[d];
#pragma unroll
            for (int bl = 0; bl < RPB; bl++) {
                float4 hv = *(const float4*)&hsh[bl][d];
                acc[bl] += wv.x * hv.x + wv.y * hv.y + wv.z * hv.z + wv.w * hv.w;
            }
        }
        float bb = b_h2h[tid];
#pragma unroll
        for (int bl = 0; bl < RPB; bl++)
            hp[(size_t)(b0 + bl) * HD + tid] = acc[bl] + bb;
    }
}

// ---------------------------------------------------------------------------
// attnctx: e scores + softmax + context.  One batch row per block.
// ---------------------------------------------------------------------------
__global__ __launch_bounds__(256) void attnctx_kernel(
    const float* __restrict__ enc, const float* __restrict__ Hproj,
    const float* __restrict__ hp, const float* __restrict__ w_score,
    float* __restrict__ ctx)
{
    __shared__ float hpsh[HD];
    __shared__ float wssh[HD];
    __shared__ float esh[TT];

    const int tid = threadIdx.x;
    const int b = blockIdx.x;

    hpsh[tid] = hp[(size_t)b * HD + tid];
    wssh[tid] = w_score[tid];
    __syncthreads();

    {
        int t = tid >> 3, sl = tid & 7;
        int d0 = sl * 32;
        const float* hpr = &Hproj[((size_t)b * TT + t) * HD + d0];
        float e = 0.0f;
#pragma unroll
        for (int d = 0; d < 32; d += 4) {
            float4 hv = *(const float4*)&hpr[d];
            float4 pv = *(const float4*)&hpsh[d0 + d];
            float4 wv = *(const float4*)&wssh[d0 + d];
            e += wv.x * tanhf(hv.x + pv.x);
            e += wv.y * tanhf(hv.y + pv.y);
            e += wv.z * tanhf(hv.z + pv.z);
            e += wv.w * tanhf(hv.w + pv.w);
        }
        e += __shfl_down(e, 4);
        e += __shfl_down(e, 2);
        e += __shfl_down(e, 1);
        if (sl == 0) esh[t] = e;
    }
    __syncthreads();

    if (tid < 32) {
        float v = esh[tid];
        float m = v;
#pragma unroll
        for (int o = 16; o > 0; o >>= 1) m = fmaxf(m, __shfl_xor(m, o));
        float p = expf(v - m);
        float s = p;
#pragma unroll
        for (int o = 16; o > 0; o >>= 1) s += __shfl_xor(s, o);
        esh[tid] = p / s;
    }
    __syncthreads();

    {
        float acc = 0.0f;
        const float* er = &enc[(size_t)b * TT * DIN + tid];
#pragma unroll
        for (int t = 0; t < TT; t++)
            acc += esh[t] * er[(size_t)t * DIN];
        ctx[(size_t)b * DIN + tid] = acc;
    }
}

// ---------------------------------------------------------------------------
extern "C" void kernel_launch(void* const* d_in, const int* in_sizes, int n_in,
                              void* d_out, int out_size, void* d_ws, size_t ws_size,
                              hipStream_t stream)
{
    const float* enc     = (const float*)d_in[0];
    const int*   text    = (const int*)d_in[1];
    const float* w_i2h   = (const float*)d_in[4];
    const float* w_h2h   = (const float*)d_in[5];
    const float* b_h2h   = (const float*)d_in[6];
    const float* w_score = (const float*)d_in[7];
    const float* w_ih    = (const float*)d_in[8];
    const float* w_hh    = (const float*)d_in[9];
    const float* b_ih    = (const float*)d_in[10];
    const float* b_hh    = (const float*)d_in[11];
    const float* w_gen   = (const float*)d_in[12];
    const float* b_gen   = (const float*)d_in[13];
    float* out = (float*)d_out;

    char* ws = (char*)d_ws;
    float*    Hproj = (float*)ws;                                  // 32 MB
    float*    hbuf  = (float*)(ws + (size_t)33554432);             // 1 MB
    float*    cbuf  = hbuf + (size_t)NB * HD;                      // 1 MB
    float*    hpbuf = cbuf + (size_t)NB * HD;                      // 1 MB
    float*    ctxb  = hpbuf + (size_t)NB * HD;                     // 1 MB
    float*    gates = ctxb + (size_t)NB * DIN;                     // 4 MB
    ushort_t* B2g   = (ushort_t*)(gates + (size_t)NB * 4 * HD);    // 3 MB
    ushort_t* B2i   = B2g + (size_t)1024 * 1536;                   // 384 KB

    hipMemsetAsync(hbuf, 0, (size_t)2 * NB * HD * sizeof(float), stream);

    prep_B2g<<<1024, 256, 0, stream>>>(w_ih, w_hh, B2g);
    prep_B2i<<<256, 256, 0, stream>>>(w_i2h, B2i);
    hproj_mfma<<<dim3(256, 2), 256, 0, stream>>>(enc, B2i, Hproj);

    for (int s = 0; s < NSTEP; s++) {
        recur_kernel<<<NB / RPB, 256, 0, stream>>>(gates, w_h2h, b_h2h, w_gen, b_gen,
                                                   hbuf, cbuf, hpbuf, out, s);
        attnctx_kernel<<<NB, 256, 0, stream>>>(enc, Hproj, hpbuf, w_score, ctxb);
        gates_mfma<<<dim3(8, 16), 256, 0, stream>>>(ctxb, hbuf, B2g, b_ih, b_hh,
                                                    w_ih, text, s, gates);
    }
    recur_kernel<<<NB / RPB, 256, 0, stream>>>(gates, w_h2h, b_h2h, w_gen, b_gen,
                                               hbuf, cbuf, hpbuf, out, NSTEP);
}

// Round 4
// 1190.286 us; speedup vs baseline: 1.8478x; 1.8478x over previous
//
#include <hip/hip_runtime.h>

#define NB 1024   // batch
#define TT 32     // encoder length
#define DIN 256   // input dim
#define HD 256    // hidden dim
#define NC 38     // classes
#define NSTEP 26  // decode steps

typedef unsigned short ushort_t;
typedef __attribute__((ext_vector_type(8))) short bf16x8;
typedef __attribute__((ext_vector_type(8))) unsigned short us8;
typedef __attribute__((ext_vector_type(4))) float f32x4;

#define GLOAD_LDS16(g, l) \
  __builtin_amdgcn_global_load_lds((const __attribute__((address_space(1))) unsigned int*)(g), \
                                   (__attribute__((address_space(3))) unsigned int*)(l), 16, 0, 0)

__device__ __forceinline__ unsigned short f2bf(float x) {
    union { float f; unsigned u; } v; v.f = x;
    unsigned r = v.u + 0x7fff + ((v.u >> 16) & 1);   // RNE
    return (unsigned short)(r >> 16);
}
__device__ __forceinline__ float bf2f(unsigned short h) {
    union { unsigned u; float f; } v; v.u = ((unsigned)h) << 16;
    return v.f;
}
__device__ __forceinline__ float fast_tanh(float x) {
    float xc = fminf(fmaxf(x, -15.f), 15.f);
    float z = __expf(2.f * xc);
    return (z - 1.f) * __builtin_amdgcn_rcpf(z + 1.f);
}
__device__ __forceinline__ float fast_sig(float x) {
    return __builtin_amdgcn_rcpf(1.f + __expf(-x));
}

// ---------------------------------------------------------------------------
// Weight prep: split-bf16.  B2g row j: [hi(W) 512 | lo(W) 512 | hi(W) 512],
// W = [w_ih[:, :256] | w_hh].
// ---------------------------------------------------------------------------
__global__ void prep_B2g(const float* __restrict__ w_ih, const float* __restrict__ w_hh,
                         ushort_t* __restrict__ B2)
{
    int j = blockIdx.x;  // 1024 rows
    for (int k = threadIdx.x; k < 512; k += 256) {
        float x = (k < 256) ? w_ih[(size_t)j * 294 + k] : w_hh[(size_t)j * 256 + (k - 256)];
        unsigned short hi = f2bf(x);
        unsigned short lo = f2bf(x - bf2f(hi));
        size_t r = (size_t)j * 1536;
        B2[r + k] = hi; B2[r + 512 + k] = lo; B2[r + 1024 + k] = hi;
    }
}

__global__ void prep_B2i(const float* __restrict__ w_i2h, ushort_t* __restrict__ B2i)
{
    int n = blockIdx.x;  // 256 rows
    int k = threadIdx.x;
    float x = w_i2h[(size_t)n * 256 + k];
    unsigned short hi = f2bf(x);
    unsigned short lo = f2bf(x - bf2f(hi));
    size_t r = (size_t)n * 768;
    B2i[r + k] = hi; B2i[r + 256 + k] = lo; B2i[r + 512 + k] = hi;
}

// ---------------------------------------------------------------------------
// hproj MFMA: Hproj[m][n] = sum_k enc[m][k] * w_i2h[n][k]
// M=32768, N=256, virtual K=768 (A parts [hi|hi|lo] from fp32 enc on the fly).
// ---------------------------------------------------------------------------
__global__ __launch_bounds__(256) void hproj_mfma(
    const float* __restrict__ enc, const ushort_t* __restrict__ B2i,
    float* __restrict__ Hproj)
{
    __shared__ ushort_t lA[128 * 64];
    __shared__ ushort_t lB[128 * 64];

    const int tid = threadIdx.x;
    const int lane = tid & 63, wid = tid >> 6;
    const int wm = wid >> 1, wn = wid & 1;
    const int m0 = blockIdx.x * 128, n0 = blockIdx.y * 128;

    f32x4 acc[4][4];
    const f32x4 fz = {0.f, 0.f, 0.f, 0.f};
#pragma unroll
    for (int i = 0; i < 4; i++)
#pragma unroll
        for (int j = 0; j < 4; j++) acc[i][j] = fz;

    for (int kc = 0; kc < 12; kc++) {
#pragma unroll
        for (int i = 0; i < 4; i++) {
            int cpos = tid + i * 256;
            int n = cpos >> 3, gp = cpos & 7;
            int gl = gp ^ (n & 7);
            const ushort_t* src = &B2i[(size_t)(n0 + n) * 768 + kc * 64 + gl * 8];
            GLOAD_LDS16(src, &lB[cpos * 8]);
        }
#pragma unroll
        for (int i = 0; i < 4; i++) {
            int cpos = tid + i * 256;
            int m = cpos >> 3, gp = cpos & 7;
            int gl = gp ^ (m & 7);
            int vk = kc * 64 + gl * 8;
            int part = vk >> 8;
            int ko = vk & 255;
            const float* src = &enc[(size_t)(m0 + m) * 256 + ko];
            float4 x0 = *(const float4*)src;
            float4 x1 = *(const float4*)(src + 4);
            float xs[8] = {x0.x, x0.y, x0.z, x0.w, x1.x, x1.y, x1.z, x1.w};
            us8 v;
            if (part < 2) {
#pragma unroll
                for (int j = 0; j < 8; j++) v[j] = f2bf(xs[j]);
            } else {
#pragma unroll
                for (int j = 0; j < 8; j++) {
                    unsigned short hh = f2bf(xs[j]);
                    v[j] = f2bf(xs[j] - bf2f(hh));
                }
            }
            *(us8*)&lA[cpos * 8] = v;
        }
        asm volatile("s_waitcnt vmcnt(0)" ::: "memory");
        __syncthreads();

#pragma unroll
        for (int kk = 0; kk < 2; kk++) {
            bf16x8 af[4], bfr[4];
            int g = kk * 4 + (lane >> 4);
#pragma unroll
            for (int mi = 0; mi < 4; mi++) {
                int m = wm * 64 + mi * 16 + (lane & 15);
                af[mi] = *(const bf16x8*)&lA[m * 64 + ((g ^ (m & 7)) << 3)];
            }
#pragma unroll
            for (int ni = 0; ni < 4; ni++) {
                int n = wn * 64 + ni * 16 + (lane & 15);
                bfr[ni] = *(const bf16x8*)&lB[n * 64 + ((g ^ (n & 7)) << 3)];
            }
#pragma unroll
            for (int mi = 0; mi < 4; mi++)
#pragma unroll
                for (int ni = 0; ni < 4; ni++)
                    acc[mi][ni] = __builtin_amdgcn_mfma_f32_16x16x32_bf16(af[mi], bfr[ni], acc[mi][ni], 0, 0, 0);
        }
        __syncthreads();
    }

#pragma unroll
    for (int mi = 0; mi < 4; mi++)
#pragma unroll
        for (int r = 0; r < 4; r++) {
            int row = m0 + wm * 64 + mi * 16 + (lane >> 4) * 4 + r;
#pragma unroll
            for (int ni = 0; ni < 4; ni++) {
                int col = n0 + wn * 64 + ni * 16 + (lane & 15);
                Hproj[(size_t)row * 256 + col] = acc[mi][ni][r];
            }
        }
}

// ---------------------------------------------------------------------------
// gates_pipe: gates = x @ W.T (+biases +onehot col), pure bf16-staged,
// double-buffered, counted vmcnt.  A2[b] = [hi(ctx)|hi(h)|lo(ctx)|lo(h)].
// M=1024, N=1024, virtual K=1536.  BM=BN=64, BK=128, grid (16,16)=256 blocks.
// ---------------------------------------------------------------------------
__global__ __launch_bounds__(256) void gates_pipe(
    const ushort_t* __restrict__ A2, const ushort_t* __restrict__ B2,
    const float* __restrict__ b_ih, const float* __restrict__ b_hh,
    const float* __restrict__ w_ih, const int* __restrict__ text,
    int step, float* __restrict__ gates)
{
    __shared__ ushort_t lA[2][64 * 128];   // 16 KB x2
    __shared__ ushort_t lB[2][64 * 128];   // 16 KB x2

    const int tid = threadIdx.x;
    const int lane = tid & 63, wid = tid >> 6;
    const int wm = wid >> 1, wn = wid & 1;
    const int m0 = blockIdx.x * 64, n0 = blockIdx.y * 64;

    f32x4 acc[2][2];
    const f32x4 fz = {0.f, 0.f, 0.f, 0.f};
    acc[0][0] = fz; acc[0][1] = fz; acc[1][0] = fz; acc[1][1] = fz;

    auto stage = [&](int t, int buf) {
#pragma unroll
        for (int i = 0; i < 4; i++) {
            int cpos = tid + i * 256;          // 0..1023
            int m = cpos >> 4, p = cpos & 15;
            int g = p ^ (m & 7);
            int vk = t * 128 + g * 8;
            int acol = (vk < 512) ? vk : vk - 512;
            GLOAD_LDS16(&A2[(size_t)(m0 + m) * 1024 + acol], &lA[buf][cpos * 8]);
        }
#pragma unroll
        for (int i = 0; i < 4; i++) {
            int cpos = tid + i * 256;
            int n = cpos >> 4, p = cpos & 15;
            int g = p ^ (n & 7);
            GLOAD_LDS16(&B2[(size_t)(n0 + n) * 1536 + t * 128 + g * 8], &lB[buf][cpos * 8]);
        }
    };

    stage(0, 0);
    stage(1, 1);

    for (int t = 0; t < 12; t++) {
        int cur = t & 1;
        if (t < 11) asm volatile("s_waitcnt vmcnt(8)" ::: "memory");
        else        asm volatile("s_waitcnt vmcnt(0)" ::: "memory");
        __syncthreads();
#pragma unroll
        for (int kk = 0; kk < 4; kk++) {
            int g = kk * 4 + (lane >> 4);
            bf16x8 af[2], bfr[2];
#pragma unroll
            for (int mi = 0; mi < 2; mi++) {
                int m = wm * 32 + mi * 16 + (lane & 15);
                af[mi] = *(const bf16x8*)&lA[cur][m * 128 + ((g ^ (m & 7)) << 3)];
            }
#pragma unroll
            for (int ni = 0; ni < 2; ni++) {
                int n = wn * 32 + ni * 16 + (lane & 15);
                bfr[ni] = *(const bf16x8*)&lB[cur][n * 128 + ((g ^ (n & 7)) << 3)];
            }
#pragma unroll
            for (int mi = 0; mi < 2; mi++)
#pragma unroll
                for (int ni = 0; ni < 2; ni++)
                    acc[mi][ni] = __builtin_amdgcn_mfma_f32_16x16x32_bf16(af[mi], bfr[ni], acc[mi][ni], 0, 0, 0);
        }
        __syncthreads();
        if (t + 2 < 12) stage(t + 2, cur);
    }

    const int r4 = (lane >> 4) * 4;
#pragma unroll
    for (int mi = 0; mi < 2; mi++)
#pragma unroll
        for (int r = 0; r < 4; r++) {
            int row = m0 + wm * 32 + mi * 16 + r4 + r;
            int cl = text[row * NSTEP + step];
#pragma unroll
            for (int ni = 0; ni < 2; ni++) {
                int col = n0 + wn * 32 + ni * 16 + (lane & 15);
                float v = acc[mi][ni][r] + b_ih[col] + b_hh[col]
                        + w_ih[(size_t)col * 294 + 256 + cl];
                gates[(size_t)row * 1024 + col] = v;
            }
        }
}

// ---------------------------------------------------------------------------
// fused_step: LSTM(step-1) + probs(step-1) + hp + scores + softmax + context
//             + A2 hi/lo write.  256 blocks x 256 threads, 4 rows/block.
// ---------------------------------------------------------------------------
__global__ __launch_bounds__(256) void fused_step(
    const float* __restrict__ gates,
    const float* __restrict__ w_h2h, const float* __restrict__ b_h2h,
    const float* __restrict__ w_gen, const float* __restrict__ b_gen,
    const float* __restrict__ w_score,
    const float* __restrict__ enc, const float* __restrict__ Hproj,
    float* __restrict__ h, float* __restrict__ c,
    ushort_t* __restrict__ A2, float* __restrict__ probs, int step)
{
    __shared__ float hsh[4][HD];
    __shared__ float hpsh[4][HD];
    __shared__ float esh[4][TT];
    __shared__ float wssh[HD];

    const int tid = threadIdx.x;
    const int b0 = blockIdx.x * 4;

    wssh[tid] = w_score[tid];

    if (step > 0) {
#pragma unroll
        for (int it = 0; it < 4; it++) {
            int idx = tid + it * 256;
            int bl = idx >> 8, hh = idx & 255;
            int b = b0 + bl;
            float gi = gates[(size_t)b * 1024 + hh];
            float gf = gates[(size_t)b * 1024 + 256 + hh];
            float gg = gates[(size_t)b * 1024 + 512 + hh];
            float go = gates[(size_t)b * 1024 + 768 + hh];
            float cv = c[(size_t)b * HD + hh];
            float cn = fast_sig(gf) * cv + fast_sig(gi) * fast_tanh(gg);
            float hn = fast_sig(go) * fast_tanh(cn);
            c[(size_t)b * HD + hh] = cn;
            h[(size_t)b * HD + hh] = hn;
            hsh[bl][hh] = hn;
            unsigned short hi_ = f2bf(hn);
            A2[(size_t)b * 1024 + 256 + hh] = hi_;
            A2[(size_t)b * 1024 + 768 + hh] = f2bf(hn - bf2f(hi_));
        }
        __syncthreads();
        {
            int bl = tid >> 6, j = tid & 63;
            if (j < NC) {
                float s = b_gen[j];
                const float* wg = &w_gen[(size_t)j * HD];
                for (int d = 0; d < HD; d += 4) {
                    float4 wv = *(const float4*)&wg[d];
                    float4 hv = *(const float4*)&hsh[bl][d];
                    s += wv.x * hv.x + wv.y * hv.y + wv.z * hv.z + wv.w * hv.w;
                }
                probs[((size_t)(b0 + bl) * NSTEP + (step - 1)) * NC + j] = s;
            }
        }
    } else {
#pragma unroll
        for (int it = 0; it < 4; it++) {
            int idx = tid + it * 256;
            int bl = idx >> 8, hh = idx & 255;
            hsh[bl][hh] = h[(size_t)(b0 + bl) * HD + hh];
        }
    }
    __syncthreads();
    if (step >= NSTEP) return;

    // hp[b][j] = dot(w_h2h[j], h[b]) + b_h2h[j], j = tid
    {
        float acc[4] = {0.f, 0.f, 0.f, 0.f};
        const float* wr = &w_h2h[(size_t)tid * HD];
        for (int d = 0; d < HD; d += 4) {
            float4 wv = *(const float4*)&wr[d];
#pragma unroll
            for (int bl = 0; bl < 4; bl++) {
                float4 hv = *(const float4*)&hsh[bl][d];
                acc[bl] += wv.x * hv.x + wv.y * hv.y + wv.z * hv.z + wv.w * hv.w;
            }
        }
        float bb = b_h2h[tid];
#pragma unroll
        for (int bl = 0; bl < 4; bl++) hpsh[bl][tid] = acc[bl] + bb;
    }
    __syncthreads();

    // scores: 2 threads per (bl,t), 128 d each
    {
        int pair = tid >> 1, half = tid & 1;
        int bl = pair >> 5, t = pair & 31;
        int d0 = half * 128;
        const float* hpr = &Hproj[((size_t)(b0 + bl) * TT + t) * HD + d0];
        const float* pv = &hpsh[bl][d0];
        const float* wv = &wssh[d0];
        float e = 0.f;
#pragma unroll 8
        for (int d = 0; d < 128; d += 4) {
            float4 hq = *(const float4*)&hpr[d];
            float4 pq = *(const float4*)&pv[d];
            float4 wq = *(const float4*)&wv[d];
            e += wq.x * fast_tanh(hq.x + pq.x);
            e += wq.y * fast_tanh(hq.y + pq.y);
            e += wq.z * fast_tanh(hq.z + pq.z);
            e += wq.w * fast_tanh(hq.w + pq.w);
        }
        e += __shfl_xor(e, 1);
        if (half == 0) esh[bl][t] = e;
    }
    __syncthreads();

    // softmax over 32 t per row; 4 rows on lanes of 2 waves (masks stay <32)
    if (tid < 128) {
        int bl = tid >> 5, l = tid & 31;
        float v = esh[bl][l];
        float m = v;
#pragma unroll
        for (int o = 16; o > 0; o >>= 1) m = fmaxf(m, __shfl_xor(m, o));
        float p = __expf(v - m);
        float s = p;
#pragma unroll
        for (int o = 16; o > 0; o >>= 1) s += __shfl_xor(s, o);
        esh[bl][l] = p * __builtin_amdgcn_rcpf(s);
    }
    __syncthreads();

    // context + A2 ctx hi/lo write; d = tid
    {
        int d = tid;
#pragma unroll
        for (int bl = 0; bl < 4; bl++) {
            const float* er = &enc[(size_t)(b0 + bl) * TT * DIN + d];
            float a = 0.f;
#pragma unroll 8
            for (int t = 0; t < TT; t++)
                a += esh[bl][t] * er[(size_t)t * DIN];
            unsigned short hi_ = f2bf(a);
            A2[(size_t)(b0 + bl) * 1024 + d] = hi_;
            A2[(size_t)(b0 + bl) * 1024 + 512 + d] = f2bf(a - bf2f(hi_));
        }
    }
}

// ---------------------------------------------------------------------------
extern "C" void kernel_launch(void* const* d_in, const int* in_sizes, int n_in,
                              void* d_out, int out_size, void* d_ws, size_t ws_size,
                              hipStream_t stream)
{
    const float* enc     = (const float*)d_in[0];
    const int*   text    = (const int*)d_in[1];
    const float* w_i2h   = (const float*)d_in[4];
    const float* w_h2h   = (const float*)d_in[5];
    const float* b_h2h   = (const float*)d_in[6];
    const float* w_score = (const float*)d_in[7];
    const float* w_ih    = (const float*)d_in[8];
    const float* w_hh    = (const float*)d_in[9];
    const float* b_ih    = (const float*)d_in[10];
    const float* b_hh    = (const float*)d_in[11];
    const float* w_gen   = (const float*)d_in[12];
    const float* b_gen   = (const float*)d_in[13];
    float* out = (float*)d_out;

    char* ws = (char*)d_ws;
    float*    Hproj = (float*)ws;                                  // 32 MB
    float*    hbuf  = (float*)(ws + (size_t)33554432);             // 1 MB
    float*    cbuf  = hbuf + (size_t)NB * HD;                      // 1 MB
    ushort_t* A2    = (ushort_t*)(cbuf + (size_t)NB * HD);         // 2 MB
    float*    gates = (float*)(A2 + (size_t)NB * 1024);            // 4 MB
    ushort_t* B2g   = (ushort_t*)(gates + (size_t)NB * 4 * HD);    // 3 MB
    ushort_t* B2i   = B2g + (size_t)1024 * 1536;                   // 384 KB

    // zero h, c, A2 (contiguous: 1+1+2 MB)
    hipMemsetAsync(hbuf, 0, (size_t)4 * 1024 * 1024, stream);

    prep_B2g<<<1024, 256, 0, stream>>>(w_ih, w_hh, B2g);
    prep_B2i<<<256, 256, 0, stream>>>(w_i2h, B2i);
    hproj_mfma<<<dim3(256, 2), 256, 0, stream>>>(enc, B2i, Hproj);

    for (int s = 0; s < NSTEP; s++) {
        fused_step<<<NB / 4, 256, 0, stream>>>(gates, w_h2h, b_h2h, w_gen, b_gen,
                                               w_score, enc, Hproj, hbuf, cbuf,
                                               A2, out, s);
        gates_pipe<<<dim3(16, 16), 256, 0, stream>>>(A2, B2g, b_ih, b_hh,
                                                     w_ih, text, s, gates);
    }
    fused_step<<<NB / 4, 256, 0, stream>>>(gates, w_h2h, b_h2h, w_gen, b_gen,
                                           w_score, enc, Hproj, hbuf, cbuf,
                                           A2, out, NSTEP);
}

// Round 5
// 1190.274 us; speedup vs baseline: 1.8479x; 1.0000x over previous
//
#include <hip/hip_runtime.h>

#define NB 1024   // batch
#define TT 32     // encoder length
#define DIN 256   // input dim
#define HD 256    // hidden dim
#define NC 38     // classes
#define NSTEP 26  // decode steps

typedef unsigned short ushort_t;
typedef __attribute__((ext_vector_type(8))) short bf16x8;
typedef __attribute__((ext_vector_type(8))) unsigned short us8;
typedef __attribute__((ext_vector_type(4))) float f32x4;

#define GLOAD_LDS16(g, l) \
  __builtin_amdgcn_global_load_lds((const __attribute__((address_space(1))) unsigned int*)(g), \
                                   (__attribute__((address_space(3))) unsigned int*)(l), 16, 0, 0)

__device__ __forceinline__ unsigned short f2bf(float x) {
    union { float f; unsigned u; } v; v.f = x;
    unsigned r = v.u + 0x7fff + ((v.u >> 16) & 1);   // RNE
    return (unsigned short)(r >> 16);
}
__device__ __forceinline__ float bf2f(unsigned short h) {
    union { unsigned u; float f; } v; v.u = ((unsigned)h) << 16;
    return v.f;
}
__device__ __forceinline__ float fast_tanh(float x) {
    float xc = fminf(fmaxf(x, -15.f), 15.f);
    float z = __expf(2.f * xc);
    return (z - 1.f) * __builtin_amdgcn_rcpf(z + 1.f);
}
__device__ __forceinline__ float fast_sig(float x) {
    return __builtin_amdgcn_rcpf(1.f + __expf(-x));
}

// ---------------------------------------------------------------------------
// Weight prep: split-bf16.  B2g row j: [hi(W) 512 | lo(W) 512 | hi(W) 512]
// ---------------------------------------------------------------------------
__global__ void prep_B2g(const float* __restrict__ w_ih, const float* __restrict__ w_hh,
                         ushort_t* __restrict__ B2)
{
    int j = blockIdx.x;  // 1024 rows
    for (int k = threadIdx.x; k < 512; k += 256) {
        float x = (k < 256) ? w_ih[(size_t)j * 294 + k] : w_hh[(size_t)j * 256 + (k - 256)];
        unsigned short hi = f2bf(x);
        unsigned short lo = f2bf(x - bf2f(hi));
        size_t r = (size_t)j * 1536;
        B2[r + k] = hi; B2[r + 512 + k] = lo; B2[r + 1024 + k] = hi;
    }
}

__global__ void prep_B2i(const float* __restrict__ w_i2h, ushort_t* __restrict__ B2i)
{
    int n = blockIdx.x;  // 256 rows
    int k = threadIdx.x;
    float x = w_i2h[(size_t)n * 256 + k];
    unsigned short hi = f2bf(x);
    unsigned short lo = f2bf(x - bf2f(hi));
    size_t r = (size_t)n * 768;
    B2i[r + k] = hi; B2i[r + 256 + k] = lo; B2i[r + 512 + k] = hi;
}

// encA2 row m (32768 rows): [hi(enc) 256 | lo(enc) 256]
__global__ __launch_bounds__(256) void prep_encA2(const float* __restrict__ enc,
                                                  ushort_t* __restrict__ encA2)
{
    int base = blockIdx.x * 16;
    int k = threadIdx.x;
#pragma unroll
    for (int rr = 0; rr < 16; rr++) {
        size_t row = base + rr;
        float x = enc[row * 256 + k];
        unsigned short hi = f2bf(x);
        unsigned short lo = f2bf(x - bf2f(hi));
        encA2[row * 512 + k] = hi;
        encA2[row * 512 + 256 + k] = lo;
    }
}

// ---------------------------------------------------------------------------
// hproj_pipe: Hb[m][n] = bf16( sum_k enc[m][k]*w_i2h[n][k] )
// M=32768, N=256, virtual K=768. BM=BN=64, BK=128, grid (512,4).
// Double-buffered, counted vmcnt(8). A from encA2 [hi|lo], B from B2i.
// ---------------------------------------------------------------------------
__global__ __launch_bounds__(256) void hproj_pipe(
    const ushort_t* __restrict__ encA2, const ushort_t* __restrict__ B2i,
    ushort_t* __restrict__ Hb)
{
    __shared__ ushort_t lA[2][64 * 128];
    __shared__ ushort_t lB[2][64 * 128];

    const int tid = threadIdx.x;
    const int lane = tid & 63, wid = tid >> 6;
    const int wm = wid >> 1, wn = wid & 1;
    const int m0 = blockIdx.x * 64, n0 = blockIdx.y * 64;

    f32x4 acc[2][2];
    const f32x4 fz = {0.f, 0.f, 0.f, 0.f};
    acc[0][0] = fz; acc[0][1] = fz; acc[1][0] = fz; acc[1][1] = fz;

    auto stage = [&](int t, int buf) {
#pragma unroll
        for (int i = 0; i < 4; i++) {
            int cpos = tid + i * 256;
            int m = cpos >> 4, p = cpos & 15;
            int g = p ^ (m & 7);
            int vk = t * 128 + g * 8;
            int acol = (vk < 256) ? vk : vk - 256;   // [0,256)=hi ; lo at 256..511
            GLOAD_LDS16(&encA2[(size_t)(m0 + m) * 512 + acol], &lA[buf][cpos * 8]);
        }
#pragma unroll
        for (int i = 0; i < 4; i++) {
            int cpos = tid + i * 256;
            int n = cpos >> 4, p = cpos & 15;
            int g = p ^ (n & 7);
            GLOAD_LDS16(&B2i[(size_t)(n0 + n) * 768 + t * 128 + g * 8], &lB[buf][cpos * 8]);
        }
    };

    stage(0, 0);
    stage(1, 1);

    for (int t = 0; t < 6; t++) {
        int cur = t & 1;
        if (t < 5) asm volatile("s_waitcnt vmcnt(8)" ::: "memory");
        else       asm volatile("s_waitcnt vmcnt(0)" ::: "memory");
        __syncthreads();
#pragma unroll
        for (int kk = 0; kk < 4; kk++) {
            int g = kk * 4 + (lane >> 4);
            bf16x8 af[2], bfr[2];
#pragma unroll
            for (int mi = 0; mi < 2; mi++) {
                int m = wm * 32 + mi * 16 + (lane & 15);
                af[mi] = *(const bf16x8*)&lA[cur][m * 128 + ((g ^ (m & 7)) << 3)];
            }
#pragma unroll
            for (int ni = 0; ni < 2; ni++) {
                int n = wn * 32 + ni * 16 + (lane & 15);
                bfr[ni] = *(const bf16x8*)&lB[cur][n * 128 + ((g ^ (n & 7)) << 3)];
            }
#pragma unroll
            for (int mi = 0; mi < 2; mi++)
#pragma unroll
                for (int ni = 0; ni < 2; ni++)
                    acc[mi][ni] = __builtin_amdgcn_mfma_f32_16x16x32_bf16(af[mi], bfr[ni], acc[mi][ni], 0, 0, 0);
        }
        __syncthreads();
        if (t + 2 < 6) stage(t + 2, cur);
    }

    const int r4 = (lane >> 4) * 4;
#pragma unroll
    for (int mi = 0; mi < 2; mi++)
#pragma unroll
        for (int r = 0; r < 4; r++) {
            size_t row = m0 + wm * 32 + mi * 16 + r4 + r;
#pragma unroll
            for (int ni = 0; ni < 2; ni++) {
                int col = n0 + wn * 32 + ni * 16 + (lane & 15);
                Hb[row * 256 + col] = f2bf(acc[mi][ni][r]);
            }
        }
}

// ---------------------------------------------------------------------------
// gates_pipe: unchanged from round 4 (passed, ~5 us predicted)
// ---------------------------------------------------------------------------
__global__ __launch_bounds__(256) void gates_pipe(
    const ushort_t* __restrict__ A2, const ushort_t* __restrict__ B2,
    const float* __restrict__ b_ih, const float* __restrict__ b_hh,
    const float* __restrict__ w_ih, const int* __restrict__ text,
    int step, float* __restrict__ gates)
{
    __shared__ ushort_t lA[2][64 * 128];
    __shared__ ushort_t lB[2][64 * 128];

    const int tid = threadIdx.x;
    const int lane = tid & 63, wid = tid >> 6;
    const int wm = wid >> 1, wn = wid & 1;
    const int m0 = blockIdx.x * 64, n0 = blockIdx.y * 64;

    f32x4 acc[2][2];
    const f32x4 fz = {0.f, 0.f, 0.f, 0.f};
    acc[0][0] = fz; acc[0][1] = fz; acc[1][0] = fz; acc[1][1] = fz;

    auto stage = [&](int t, int buf) {
#pragma unroll
        for (int i = 0; i < 4; i++) {
            int cpos = tid + i * 256;
            int m = cpos >> 4, p = cpos & 15;
            int g = p ^ (m & 7);
            int vk = t * 128 + g * 8;
            int acol = (vk < 512) ? vk : vk - 512;
            GLOAD_LDS16(&A2[(size_t)(m0 + m) * 1024 + acol], &lA[buf][cpos * 8]);
        }
#pragma unroll
        for (int i = 0; i < 4; i++) {
            int cpos = tid + i * 256;
            int n = cpos >> 4, p = cpos & 15;
            int g = p ^ (n & 7);
            GLOAD_LDS16(&B2[(size_t)(n0 + n) * 1536 + t * 128 + g * 8], &lB[buf][cpos * 8]);
        }
    };

    stage(0, 0);
    stage(1, 1);

    for (int t = 0; t < 12; t++) {
        int cur = t & 1;
        if (t < 11) asm volatile("s_waitcnt vmcnt(8)" ::: "memory");
        else        asm volatile("s_waitcnt vmcnt(0)" ::: "memory");
        __syncthreads();
#pragma unroll
        for (int kk = 0; kk < 4; kk++) {
            int g = kk * 4 + (lane >> 4);
            bf16x8 af[2], bfr[2];
#pragma unroll
            for (int mi = 0; mi < 2; mi++) {
                int m = wm * 32 + mi * 16 + (lane & 15);
                af[mi] = *(const bf16x8*)&lA[cur][m * 128 + ((g ^ (m & 7)) << 3)];
            }
#pragma unroll
            for (int ni = 0; ni < 2; ni++) {
                int n = wn * 32 + ni * 16 + (lane & 15);
                bfr[ni] = *(const bf16x8*)&lB[cur][n * 128 + ((g ^ (n & 7)) << 3)];
            }
#pragma unroll
            for (int mi = 0; mi < 2; mi++)
#pragma unroll
                for (int ni = 0; ni < 2; ni++)
                    acc[mi][ni] = __builtin_amdgcn_mfma_f32_16x16x32_bf16(af[mi], bfr[ni], acc[mi][ni], 0, 0, 0);
        }
        __syncthreads();
        if (t + 2 < 12) stage(t + 2, cur);
    }

    const int r4 = (lane >> 4) * 4;
#pragma unroll
    for (int mi = 0; mi < 2; mi++)
#pragma unroll
        for (int r = 0; r < 4; r++) {
            int row = m0 + wm * 32 + mi * 16 + r4 + r;
            int cl = text[row * NSTEP + step];
#pragma unroll
            for (int ni = 0; ni < 2; ni++) {
                int col = n0 + wn * 32 + ni * 16 + (lane & 15);
                float v = acc[mi][ni][r] + b_ih[col] + b_hh[col]
                        + w_ih[(size_t)col * 294 + 256 + cl];
                gates[(size_t)row * 1024 + col] = v;
            }
        }
}

// ---------------------------------------------------------------------------
// recur_step: LSTM(step-1) + probs(step-1) + hp(step) + A2 h-part write.
// 256 blocks x 256 threads, 4 rows/block (w_h2h reuse x4).
// ---------------------------------------------------------------------------
__global__ __launch_bounds__(256) void recur_step(
    const float* __restrict__ gates,
    const float* __restrict__ w_h2h, const float* __restrict__ b_h2h,
    const float* __restrict__ w_gen, const float* __restrict__ b_gen,
    float* __restrict__ h, float* __restrict__ c, float* __restrict__ hp,
    ushort_t* __restrict__ A2, float* __restrict__ probs, int step)
{
    __shared__ float hsh[4][HD];
    const int tid = threadIdx.x;
    const int b0 = blockIdx.x * 4;

    if (step > 0) {
#pragma unroll
        for (int it = 0; it < 4; it++) {
            int idx = tid + it * 256;
            int bl = idx >> 8, hh = idx & 255;
            int b = b0 + bl;
            float gi = gates[(size_t)b * 1024 + hh];
            float gf = gates[(size_t)b * 1024 + 256 + hh];
            float gg = gates[(size_t)b * 1024 + 512 + hh];
            float go = gates[(size_t)b * 1024 + 768 + hh];
            float cv = c[(size_t)b * HD + hh];
            float cn = fast_sig(gf) * cv + fast_sig(gi) * fast_tanh(gg);
            float hn = fast_sig(go) * fast_tanh(cn);
            c[(size_t)b * HD + hh] = cn;
            h[(size_t)b * HD + hh] = hn;
            hsh[bl][hh] = hn;
            unsigned short hi_ = f2bf(hn);
            A2[(size_t)b * 1024 + 256 + hh] = hi_;
            A2[(size_t)b * 1024 + 768 + hh] = f2bf(hn - bf2f(hi_));
        }
        __syncthreads();
        {
            int bl = tid >> 6, j = tid & 63;
            if (j < NC) {
                float s = b_gen[j];
                const float* wg = &w_gen[(size_t)j * HD];
                for (int d = 0; d < HD; d += 4) {
                    float4 wv = *(const float4*)&wg[d];
                    float4 hv = *(const float4*)&hsh[bl][d];
                    s += wv.x * hv.x + wv.y * hv.y + wv.z * hv.z + wv.w * hv.w;
                }
                probs[((size_t)(b0 + bl) * NSTEP + (step - 1)) * NC + j] = s;
            }
        }
    } else {
#pragma unroll
        for (int it = 0; it < 4; it++) {
            int idx = tid + it * 256;
            int bl = idx >> 8, hh = idx & 255;
            hsh[bl][hh] = h[(size_t)(b0 + bl) * HD + hh];
        }
    }
    __syncthreads();
    if (step >= NSTEP) return;

    // hp[b][j] = dot(w_h2h[j], h[b]) + b_h2h[j], j = tid
    {
        float acc[4] = {0.f, 0.f, 0.f, 0.f};
        const float* wr = &w_h2h[(size_t)tid * HD];
        for (int d = 0; d < HD; d += 4) {
            float4 wv = *(const float4*)&wr[d];
#pragma unroll
            for (int bl = 0; bl < 4; bl++) {
                float4 hv = *(const float4*)&hsh[bl][d];
                acc[bl] += wv.x * hv.x + wv.y * hv.y + wv.z * hv.z + wv.w * hv.w;
            }
        }
        float bb = b_h2h[tid];
#pragma unroll
        for (int bl = 0; bl < 4; bl++)
            hp[(size_t)(b0 + bl) * HD + tid] = acc[bl] + bb;
    }
}

// ---------------------------------------------------------------------------
// attn_step: scores (bf16 Hproj) + softmax + context (fp32 enc) + A2 ctx.
// 1024 blocks x 256 threads, one batch row per block.
// ---------------------------------------------------------------------------
__global__ __launch_bounds__(256) void attn_step(
    const float* __restrict__ enc, const ushort_t* __restrict__ Hb,
    const float* __restrict__ hp, const float* __restrict__ w_score,
    ushort_t* __restrict__ A2)
{
    __shared__ float hpsh[HD];
    __shared__ float wssh[HD];
    __shared__ float esh[TT];

    const int tid = threadIdx.x;
    const int b = blockIdx.x;

    hpsh[tid] = hp[(size_t)b * HD + tid];
    wssh[tid] = w_score[tid];
    __syncthreads();

    // scores: 8 threads per t, 32 d each, bf16 Hproj via us8 loads
    {
        int t = tid >> 3, sl = tid & 7;
        const ushort_t* hr = &Hb[((size_t)b * TT + t) * HD];
        float e = 0.f;
#pragma unroll
        for (int j = 0; j < 4; j++) {
            int d0 = sl * 8 + j * 64;
            us8 hv = *(const us8*)&hr[d0];
#pragma unroll
            for (int k = 0; k < 8; k++) {
                int d = d0 + k;
                e += wssh[d] * fast_tanh(bf2f(hv[k]) + hpsh[d]);
            }
        }
        e += __shfl_xor(e, 4);
        e += __shfl_xor(e, 2);
        e += __shfl_xor(e, 1);
        if (sl == 0) esh[t] = e;
    }
    __syncthreads();

    if (tid < 32) {
        float v = esh[tid];
        float m = v;
#pragma unroll
        for (int o = 16; o > 0; o >>= 1) m = fmaxf(m, __shfl_xor(m, o));
        float p = __expf(v - m);
        float s = p;
#pragma unroll
        for (int o = 16; o > 0; o >>= 1) s += __shfl_xor(s, o);
        esh[tid] = p * __builtin_amdgcn_rcpf(s);
    }
    __syncthreads();

    // context d = tid over 32 t; write A2 ctx hi/lo
    {
        float a = 0.f;
        const float* er = &enc[(size_t)b * TT * DIN + tid];
#pragma unroll 8
        for (int t = 0; t < TT; t++)
            a += esh[t] * er[(size_t)t * DIN];
        unsigned short hi_ = f2bf(a);
        A2[(size_t)b * 1024 + tid] = hi_;
        A2[(size_t)b * 1024 + 512 + tid] = f2bf(a - bf2f(hi_));
    }
}

// ---------------------------------------------------------------------------
extern "C" void kernel_launch(void* const* d_in, const int* in_sizes, int n_in,
                              void* d_out, int out_size, void* d_ws, size_t ws_size,
                              hipStream_t stream)
{
    const float* enc     = (const float*)d_in[0];
    const int*   text    = (const int*)d_in[1];
    const float* w_i2h   = (const float*)d_in[4];
    const float* w_h2h   = (const float*)d_in[5];
    const float* b_h2h   = (const float*)d_in[6];
    const float* w_score = (const float*)d_in[7];
    const float* w_ih    = (const float*)d_in[8];
    const float* w_hh    = (const float*)d_in[9];
    const float* b_ih    = (const float*)d_in[10];
    const float* b_hh    = (const float*)d_in[11];
    const float* w_gen   = (const float*)d_in[12];
    const float* b_gen   = (const float*)d_in[13];
    float* out = (float*)d_out;

    const size_t MB = 1024 * 1024;
    char* ws = (char*)d_ws;
    ushort_t* Hb    = (ushort_t*)ws;                       // 16 MB  [0,16)
    float*    hbuf  = (float*)(ws + 16 * MB);              // 1 MB   [16,17)
    float*    cbuf  = (float*)(ws + 17 * MB);              // 1 MB   [17,18)
    float*    hpbuf = (float*)(ws + 18 * MB);              // 1 MB   [18,19)
    ushort_t* B2g   = (ushort_t*)(ws + 19 * MB);           // 3 MB   [19,22)
    ushort_t* B2i   = (ushort_t*)(ws + 22 * MB);           // .375   [22,22.5)
    // overlap region S at 23 MB: encA2 (32 MB, dead after hproj_pipe)
    // hosts A2 (2 MB) + gates (4 MB) afterwards.
    ushort_t* encA2 = (ushort_t*)(ws + 23 * MB);           // 32 MB  [23,55)
    ushort_t* A2    = (ushort_t*)(ws + 23 * MB);           // 2 MB
    float*    gates = (float*)(ws + 25 * MB);              // 4 MB

    // zero h and c (contiguous)
    hipMemsetAsync(hbuf, 0, 2 * MB, stream);

    prep_B2g<<<1024, 256, 0, stream>>>(w_ih, w_hh, B2g);
    prep_B2i<<<256, 256, 0, stream>>>(w_i2h, B2i);
    prep_encA2<<<2048, 256, 0, stream>>>(enc, encA2);
    hproj_pipe<<<dim3(512, 4), 256, 0, stream>>>(encA2, B2i, Hb);
    // encA2 dead from here; zero A2 (h parts must be 0 for step 0)
    hipMemsetAsync(A2, 0, 2 * MB, stream);

    for (int s = 0; s < NSTEP; s++) {
        recur_step<<<256, 256, 0, stream>>>(gates, w_h2h, b_h2h, w_gen, b_gen,
                                            hbuf, cbuf, hpbuf, A2, out, s);
        attn_step<<<1024, 256, 0, stream>>>(enc, Hb, hpbuf, w_score, A2);
        gates_pipe<<<dim3(16, 16), 256, 0, stream>>>(A2, B2g, b_ih, b_hh,
                                                     w_ih, text, s, gates);
    }
    recur_step<<<256, 256, 0, stream>>>(gates, w_h2h, b_h2h, w_gen, b_gen,
                                        hbuf, cbuf, hpbuf, A2, out, NSTEP);
}